// Round 13
// baseline (675.320 us; speedup 1.0000x reference)
//
#include <hip/hip_runtime.h>
#include <hip/hip_bf16.h>
#include <hip/hip_cooperative_groups.h>

namespace cg = cooperative_groups;

#define IN_F 256
#define OU_F 64
#define BKN 128          // nodes per bucket
#define BSHIFT 7
#define NBMAX 512        // max buckets supported
#define PCHUNK 2048      // edges per partition chunk
#define STAGE_CAP 4096   // max records staged in LDS by csr phase

typedef __attribute__((ext_vector_type(8))) short short8;
typedef __attribute__((ext_vector_type(4))) float f32x4;

struct Rec { int x; int y; };    // POD stand-in for int2 (union-safe)

__device__ inline short8 cvt8(float4 a, float4 b)
{
    union { short8 s8; __hip_bfloat162 h2[4]; } u;
    u.h2[0] = __float22bfloat162_rn(make_float2(a.x, a.y));
    u.h2[1] = __float22bfloat162_rn(make_float2(a.z, a.w));
    u.h2[2] = __float22bfloat162_rn(make_float2(b.x, b.y));
    u.h2[3] = __float22bfloat162_rn(make_float2(b.z, b.w));
    return u.s8;
}

// ---------------- LDS layouts ----------------
struct PartLds {
    int hist[NBMAX], X[NBMAX], gshift[NBMAX], s[256];
    Rec stage[PCHUNK];                        // 23.5 KB total
};
struct CsrLds { int cnt[BKN]; int cur[BKN]; Rec stage[STAGE_CAP]; };  // 33.8 KB
union MegaLds {
    unsigned short Wt[64][264];               // 33792 B (gemm)
    struct { int lh[NBMAX]; int s[256]; } hh; // hist/scan
    PartLds part;
    CsrLds  csr;
};

// ---------------- phase: GEMM hp(bf16) = h @ W (round-10 proven body) ----------------
__device__ __forceinline__ void phase_gemm(const float* __restrict__ h,
    const float* __restrict__ W, __hip_bfloat16* __restrict__ hp,
    int N, int ntiles, int bid, int nb, unsigned short (*Wt)[264])
{
    const int t = threadIdx.x;
#pragma unroll
    for (int i = 0; i < 16; ++i) {
        int p  = t + i * 512;
        int c  = p & 63;
        int k0 = (p >> 6) << 1;
        float x = W[(size_t)k0 * OU_F + c];
        float y = W[(size_t)(k0 + 1) * OU_F + c];
        __hip_bfloat162 bb = __float22bfloat162_rn(make_float2(x, y));
        *reinterpret_cast<unsigned*>(&Wt[c][k0]) = *reinterpret_cast<unsigned*>(&bb);
    }
    __syncthreads();

    const int l = t & 63, wv = t >> 6, cl = l & 15, kg = l >> 4;
    const int rg4 = wv & 3, cgrp = wv >> 2;

    short8 bfr[2][8];
#pragma unroll
    for (int n2 = 0; n2 < 2; ++n2)
#pragma unroll
        for (int ks = 0; ks < 8; ++ks)
            bfr[n2][ks] = *reinterpret_cast<const short8*>(
                &Wt[cgrp * 32 + n2 * 16 + cl][ks * 32 + kg * 8]);

    for (int tile = bid; tile < ntiles; tile += nb) {
        const int rbase = tile * 64 + rg4 * 16;
        const int r     = rbase + cl;
        const int rld   = min(r, N - 1);
        const float4* hrow = reinterpret_cast<const float4*>(h) + (size_t)rld * (IN_F / 4);

        f32x4 acc0 = (f32x4){0.f, 0.f, 0.f, 0.f};
        f32x4 acc1 = (f32x4){0.f, 0.f, 0.f, 0.f};
#pragma unroll
        for (int ks = 0; ks < 8; ++ks) {
            float4 a0 = hrow[ks * 8 + kg * 2];
            float4 a1 = hrow[ks * 8 + kg * 2 + 1];
            short8 af = cvt8(a0, a1);
            acc0 = __builtin_amdgcn_mfma_f32_16x16x32_bf16(af, bfr[0][ks], acc0, 0, 0, 0);
            acc1 = __builtin_amdgcn_mfma_f32_16x16x32_bf16(af, bfr[1][ks], acc1, 0, 0, 0);
        }
#pragma unroll
        for (int rg = 0; rg < 4; ++rg) {
            int rr = rbase + kg * 4 + rg;
            if (rr < N) {
                size_t base = (size_t)rr * OU_F + cgrp * 32 + cl;
                hp[base]      = __float2bfloat16(acc0[rg]);
                hp[base + 16] = __float2bfloat16(acc1[rg]);
            }
        }
    }
}

// ---------------- phase: histogram of col>>7 into global bcnt ----------------
__device__ __forceinline__ void phase_hist(const int* __restrict__ col,
    int* __restrict__ bcnt, int E, int NB, int bid, int nb, int* lh)
{
    const int t = threadIdx.x;
    for (int i = t; i < NBMAX; i += 512) lh[i] = 0;
    __syncthreads();
    const int n4 = E >> 2;
    const int4* c4 = (const int4*)col;
    for (int i = bid * 512 + t; i < n4; i += nb * 512) {
        int4 v = c4[i];
        atomicAdd(&lh[v.x >> BSHIFT], 1);
        atomicAdd(&lh[v.y >> BSHIFT], 1);
        atomicAdd(&lh[v.z >> BSHIFT], 1);
        atomicAdd(&lh[v.w >> BSHIFT], 1);
    }
    if (bid == 0)
        for (int e = (n4 << 2) + t; e < E; e += 512)
            atomicAdd(&lh[col[e] >> BSHIFT], 1);
    __syncthreads();
    for (int i = t; i < NB; i += 512)
        if (lh[i]) atomicAdd(&bcnt[i], lh[i]);
}

// ---------------- phase: exclusive scan (one block) ----------------
__device__ __forceinline__ void phase_scan(const int* __restrict__ bcnt,
    int* __restrict__ boffs, int* __restrict__ bcursor, int NB, int* lh, int* s)
{
    const int t = threadIdx.x;
    for (int i = t; i < NBMAX; i += 512)
        lh[i] = (i < NB) ? __hip_atomic_load(&bcnt[i], __ATOMIC_RELAXED,
                                             __HIP_MEMORY_SCOPE_AGENT) : 0;
    __syncthreads();
    int s0 = 0;
    if (t < 256) {
        s0 = lh[2 * t];
        s[t] = s0 + lh[2 * t + 1];
    }
    __syncthreads();
    for (int d = 1; d < 256; d <<= 1) {
        int v = (t < 256 && t >= d) ? s[t - d] : 0;
        __syncthreads();
        if (t < 256) s[t] += v;
        __syncthreads();
    }
    if (t < 256) {
        int excl = t ? s[t - 1] : 0;
        int i0 = 2 * t, i1 = 2 * t + 1;
        if (i0 < NB) { boffs[i0] = excl;      bcursor[i0] = excl;      }
        if (i1 < NB) { boffs[i1] = excl + s0; bcursor[i1] = excl + s0; }
        if (t == 255) boffs[NB] = s[255];
    }
}

// ---------------- phase: partition one 2048-edge chunk (round-10 proven) ----------------
__device__ __forceinline__ void phase_partition_chunk(const int* __restrict__ row,
    const int* __restrict__ col, const float* __restrict__ vals,
    int* __restrict__ bcursor, Rec* __restrict__ epk, int E, int NB,
    int c, PartLds* P)
{
    const int t = threadIdx.x;
    const int base = c * PCHUNK;
    const int n = min(PCHUNK, E - base);

    for (int i = t; i < NBMAX; i += 512) P->hist[i] = 0;
    __syncthreads();
#pragma unroll
    for (int k = 0; k < PCHUNK / 512; ++k) {
        int i = t + k * 512;
        if (i < n) atomicAdd(&P->hist[col[base + i] >> BSHIFT], 1);
    }
    __syncthreads();
    int h0 = 0;
    if (t < 256) {
        h0 = P->hist[2 * t];
        P->s[t] = h0 + P->hist[2 * t + 1];
    }
    __syncthreads();
    for (int d = 1; d < 256; d <<= 1) {
        int v = (t < 256 && t >= d) ? P->s[t - d] : 0;
        __syncthreads();
        if (t < 256) P->s[t] += v;
        __syncthreads();
    }
    if (t < 256) {
        int excl = t ? P->s[t - 1] : 0;
        P->X[2 * t]     = excl;
        P->X[2 * t + 1] = excl + h0;
    }
    __syncthreads();
    for (int i = t; i < NB; i += 512) {
        int hc = P->hist[i];
        int g = hc ? atomicAdd(&bcursor[i], hc) : 0;
        P->gshift[i] = g - P->X[i];
    }
    __syncthreads();
#pragma unroll
    for (int k = 0; k < PCHUNK / 512; ++k) {
        int i = t + k * 512;
        if (i < n) {
            int e  = base + i;
            int cv = col[e];
            int b  = cv >> BSHIFT;
            int r  = atomicAdd(&P->X[b], 1);
            unsigned pk = (unsigned)row[e] | ((unsigned)(cv & (BKN - 1)) << 17);
            P->stage[r] = Rec{(int)pk, __float_as_int(vals[e])};
        }
    }
    __syncthreads();
    const int l = t & 63, wv = t >> 6;
    for (int b = wv; b < NB; b += 8) {
        int cnt = P->hist[b];
        if (!cnt) continue;
        int src0 = P->X[b] - cnt;
        int dst0 = P->gshift[b] + src0;
        for (int j = l; j < cnt; j += 64)
            epk[dst0 + j] = P->stage[src0 + j];
    }
}

// ---------------- phase: csr one bucket (round-10 proven) ----------------
__device__ __forceinline__ void phase_csr_bucket(const Rec* __restrict__ epk,
    const int* __restrict__ boffs, Rec* __restrict__ epk2,
    int* __restrict__ node_offs, int N, int NB, int b, CsrLds* C)
{
    const int t = threadIdx.x;
    const int s = boffs[b], e = boffs[b + 1];
    const int n = e - s;
    const int node0 = b << BSHIFT;

    if (t < BKN) C->cnt[t] = 0;
    __syncthreads();
    for (int i = t; i < n; i += 512)
        atomicAdd(&C->cnt[((unsigned)epk[s + i].x) >> 17], 1);
    __syncthreads();
    if (t < 64) {
        int v0 = C->cnt[2 * t], v1 = C->cnt[2 * t + 1];
        int p = v0 + v1, sum = p;
#pragma unroll
        for (int d = 1; d < 64; d <<= 1) {
            int u = __shfl_up(sum, d);
            if (t >= d) sum += u;
        }
        int excl = sum - p;
        C->cur[2 * t]     = excl;
        C->cur[2 * t + 1] = excl + v0;
        int nd0 = node0 + 2 * t;
        if (nd0 < N)     node_offs[nd0]     = s + excl;
        if (nd0 + 1 < N) node_offs[nd0 + 1] = s + excl + v0;
    }
    if (b == NB - 1 && t == 0) node_offs[N] = e;
    __syncthreads();
    if (n <= STAGE_CAP) {
        for (int i = t; i < n; i += 512) {
            Rec r = epk[s + i];
            int pos = atomicAdd(&C->cur[((unsigned)r.x) >> 17], 1);
            C->stage[pos] = r;
        }
        __syncthreads();
        for (int i = t; i < n; i += 512)
            epk2[s + i] = C->stage[i];
    } else {
        for (int i = t; i < n; i += 512) {
            Rec r = epk[s + i];
            int pos = atomicAdd(&C->cur[((unsigned)r.x) >> 17], 1);
            epk2[s + pos] = r;
        }
    }
}

// ---------------- phase: gather, one wave per node (round-5/10 proven) ----------------
__device__ __forceinline__ void phase_gather(const __hip_bfloat16* __restrict__ hp,
    const int* __restrict__ node_offs, const Rec* __restrict__ epk2,
    float* __restrict__ out, int N, int bid, int nb)
{
    const int t = threadIdx.x, lane = t & 63, wv = t >> 6;
    for (int node = bid * 8 + wv; node < N; node += nb * 8) {
        int s = node_offs[node], e = node_offs[node + 1];
        float acc = 0.f;
        for (int base = s; base < e; base += 64) {
            int n = min(64, e - base);
            Rec m = {0, 0};
            if (lane < n) m = epk2[base + lane];
            int j = 0;
            for (; j + 4 <= n; j += 4) {
                unsigned r0 = (unsigned)__shfl(m.x, j)     & 0x1FFFFu;
                unsigned r1 = (unsigned)__shfl(m.x, j + 1) & 0x1FFFFu;
                unsigned r2 = (unsigned)__shfl(m.x, j + 2) & 0x1FFFFu;
                unsigned r3 = (unsigned)__shfl(m.x, j + 3) & 0x1FFFFu;
                float v0 = __int_as_float(__shfl(m.y, j));
                float v1 = __int_as_float(__shfl(m.y, j + 1));
                float v2 = __int_as_float(__shfl(m.y, j + 2));
                float v3 = __int_as_float(__shfl(m.y, j + 3));
                float x0 = __bfloat162float(hp[((size_t)r0 << 6) + lane]);
                float x1 = __bfloat162float(hp[((size_t)r1 << 6) + lane]);
                float x2 = __bfloat162float(hp[((size_t)r2 << 6) + lane]);
                float x3 = __bfloat162float(hp[((size_t)r3 << 6) + lane]);
                acc = fmaf(v0, x0, acc);
                acc = fmaf(v1, x1, acc);
                acc = fmaf(v2, x2, acc);
                acc = fmaf(v3, x3, acc);
            }
            for (; j < n; ++j) {
                unsigned r = (unsigned)__shfl(m.x, j) & 0x1FFFFu;
                float    v = __int_as_float(__shfl(m.y, j));
                acc = fmaf(v, __bfloat162float(hp[((size_t)r << 6) + lane]), acc);
            }
        }
        out[(size_t)node * OU_F + lane] = acc;
    }
}

// ---------------- cooperative mega-kernel ----------------
__global__ void __launch_bounds__(512, 4)
mega_kernel(const float* h, const float* W, const int* row, const int* col,
            const float* vals, __hip_bfloat16* hp, int* bcnt, int* boffs,
            int* bcursor, int* node_offs, Rec* epk, Rec* epk2, float* out,
            int N, int E, int NB, int ntiles, int nchunks)
{
    __shared__ MegaLds lds;
    cg::grid_group grid = cg::this_grid();
    const int bid = blockIdx.x, nb = gridDim.x;

    if (bid == 0)
        for (int i = threadIdx.x; i <= NBMAX; i += 512) bcnt[i] = 0;

    phase_gemm(h, W, hp, N, ntiles, bid, nb, lds.Wt);
    grid.sync(); __threadfence();

    phase_hist(col, bcnt, E, NB, bid, nb, lds.hh.lh);
    grid.sync(); __threadfence();

    if (bid == 0) phase_scan(bcnt, boffs, bcursor, NB, lds.hh.lh, lds.hh.s);
    grid.sync(); __threadfence();

    for (int c = bid; c < nchunks; c += nb) {
        phase_partition_chunk(row, col, vals, bcursor, epk, E, NB, c, &lds.part);
        __syncthreads();
    }
    grid.sync(); __threadfence();

    for (int b = bid; b < NB; b += nb) {
        phase_csr_bucket(epk, boffs, epk2, node_offs, N, NB, b, &lds.csr);
        __syncthreads();
    }
    grid.sync(); __threadfence();

    phase_gather(hp, node_offs, epk2, out, N, bid, nb);
}

// ---------------- fallback wrappers (round-10 separate-dispatch path) ----------------
__global__ void __launch_bounds__(512, 4)
gemm_sep(const float* __restrict__ h, const float* __restrict__ W,
         __hip_bfloat16* __restrict__ hp, int N, int ntiles)
{
    __shared__ unsigned short Wt[64][264];
    phase_gemm(h, W, hp, N, ntiles, blockIdx.x, gridDim.x, Wt);
}

__global__ void __launch_bounds__(512)
hist_sep(const int* __restrict__ col, int* __restrict__ bcnt, int E, int NB)
{
    __shared__ int lh[NBMAX];
    phase_hist(col, bcnt, E, NB, blockIdx.x, gridDim.x, lh);
}

__global__ void __launch_bounds__(512)
scan_sep(const int* __restrict__ bcnt, int* __restrict__ boffs,
         int* __restrict__ bcursor, int NB)
{
    __shared__ int lh[NBMAX];
    __shared__ int s[256];
    phase_scan(bcnt, boffs, bcursor, NB, lh, s);
}

__global__ void __launch_bounds__(512)
part_sep(const int* __restrict__ row, const int* __restrict__ col,
         const float* __restrict__ vals, int* __restrict__ bcursor,
         Rec* __restrict__ epk, int E, int NB)
{
    __shared__ PartLds P;
    phase_partition_chunk(row, col, vals, bcursor, epk, E, NB, blockIdx.x, &P);
}

__global__ void __launch_bounds__(512)
csr_sep(const Rec* __restrict__ epk, const int* __restrict__ boffs,
        Rec* __restrict__ epk2, int* __restrict__ node_offs, int N, int NB)
{
    __shared__ CsrLds C;
    phase_csr_bucket(epk, boffs, epk2, node_offs, N, NB, blockIdx.x, &C);
}

__global__ void __launch_bounds__(512)
gather_sep(const __hip_bfloat16* __restrict__ hp, const int* __restrict__ node_offs,
           const Rec* __restrict__ epk2, float* __restrict__ out, int N)
{
    phase_gather(hp, node_offs, epk2, out, N, blockIdx.x, gridDim.x);
}

// atomic-scatter fallback if workspace doesn't fit
__global__ void __launch_bounds__(256)
scatter_kernel(const __hip_bfloat16* __restrict__ hp, const int* __restrict__ row,
               const int* __restrict__ col, const float* __restrict__ vals,
               float* __restrict__ out, int E)
{
    unsigned int gid = blockIdx.x * 256u + threadIdx.x;
    int e = (int)(gid >> 6);
    if (e >= E) return;
    int f = (int)(gid & 63u);
    float m = vals[e] * __bfloat162float(hp[(size_t)row[e] * OU_F + f]);
    __hip_atomic_fetch_add(&out[(size_t)col[e] * OU_F + f], m,
                           __ATOMIC_RELAXED, __HIP_MEMORY_SCOPE_AGENT);
}

extern "C" void kernel_launch(void* const* d_in, const int* in_sizes, int n_in,
                              void* d_out, int out_size, void* d_ws, size_t ws_size,
                              hipStream_t stream)
{
    const float* h    = (const float*)d_in[0];
    const float* W    = (const float*)d_in[1];
    const int*   row  = (const int*)d_in[2];
    const int*   col  = (const int*)d_in[3];
    const float* vals = (const float*)d_in[4];
    float*       out  = (float*)d_out;

    const int N  = in_sizes[0] / IN_F;
    const int E  = in_sizes[2];
    const int NB = (N + BKN - 1) / BKN;
    const int ntiles  = (N + 63) / 64;
    const int nchunks = (E + PCHUNK - 1) / PCHUNK;

    char*  ws  = (char*)d_ws;
    size_t off = 0;
    auto alloc = [&](size_t bytes) -> char* {
        char* p = ws + off;
        off = (off + bytes + 255) & ~(size_t)255;
        return p;
    };
    __hip_bfloat16* hp = (__hip_bfloat16*)alloc((size_t)N * OU_F * 2);
    int* bcnt      = (int*)alloc((size_t)(NBMAX + 1) * 4);
    int* boffs     = (int*)alloc((size_t)(NBMAX + 1) * 4);
    int* bcursor   = (int*)alloc((size_t)NBMAX * 4);
    int* node_offs = (int*)alloc((size_t)(N + 1) * 4);
    Rec* epk       = (Rec*)alloc((size_t)E * 8);
    Rec* epk2      = (Rec*)alloc((size_t)E * 8);
    const bool fits = (off <= ws_size) && (NB <= NBMAX) && (N < 131072);

    if (!fits) {
        gemm_sep<<<ntiles, 512, 0, stream>>>(h, W, hp, N, ntiles);
        hipMemsetAsync(d_out, 0, (size_t)out_size * sizeof(float), stream);
        unsigned long long total = (unsigned long long)E * 64ull;
        unsigned int sgrid = (unsigned int)((total + 255ull) / 256ull);
        scatter_kernel<<<sgrid, 256, 0, stream>>>(hp, row, col, vals, out, E);
        return;
    }

    int dev = 0, coop = 0;
    hipGetDevice(&dev);
    hipDeviceGetAttribute(&coop, hipDeviceAttributeCooperativeLaunch, dev);

    bool launched = false;
    if (coop) {
        int Ni = N, Ei = E, NBi = NB, nt = ntiles, nc = nchunks;
        void* args[] = { (void*)&h, (void*)&W, (void*)&row, (void*)&col,
                         (void*)&vals, (void*)&hp, (void*)&bcnt, (void*)&boffs,
                         (void*)&bcursor, (void*)&node_offs, (void*)&epk,
                         (void*)&epk2, (void*)&out,
                         (void*)&Ni, (void*)&Ei, (void*)&NBi, (void*)&nt, (void*)&nc };
        hipError_t rc = hipLaunchCooperativeKernel(
            reinterpret_cast<void*>(mega_kernel), dim3(512), dim3(512),
            args, 0, stream);
        launched = (rc == hipSuccess);
    }

    if (!launched) {
        // round-10 proven separate-dispatch chain
        hipMemsetAsync(bcnt, 0, (size_t)(NBMAX + 1) * 4, stream);
        gemm_sep<<<ntiles, 512, 0, stream>>>(h, W, hp, N, ntiles);
        hist_sep<<<256, 512, 0, stream>>>(col, bcnt, E, NB);
        scan_sep<<<1, 512, 0, stream>>>(bcnt, boffs, bcursor, NB);
        part_sep<<<nchunks, 512, 0, stream>>>(row, col, vals, bcursor, epk, E, NB);
        csr_sep<<<NB, 512, 0, stream>>>(epk, boffs, epk2, node_offs, N, NB);
        gather_sep<<<(N + 7) / 8, 512, 0, stream>>>(hp, node_offs, epk2, out, N);
    }
}